// Round 17
// baseline (59.712 us; speedup 1.0000x reference)
//
#include <hip/hip_runtime.h>

#define NB 32
#define NN 64
#define ND 128
#define NH 256
#define LN_EPS 1e-5f
#define RP 4

typedef __attribute__((ext_vector_type(8))) short bf16x8;
typedef __attribute__((ext_vector_type(4))) float f32x4;

// ---- branchless erf-based GELU, A&S 7.1.25 (|erf err| <= 5e-4), Estrin form ----
__device__ __forceinline__ float gelu2(float x) {     // returns 2*gelu(x)
    const float au  = fabsf(x);
    const float xpa = x + au;
    const float z   = au * 0.70710678118654752440f;
    const float z2  = z * z;
    const float pc  = fmaf(0.078108f, z, 0.000972f);
    const float pb  = fmaf(0.278393f, z, 1.0f);
    const float p   = fmaf(z2, fmaf(z, pc, 0.230389f), pb);
    const float p2  = p * p;
    const float r   = __builtin_amdgcn_rcpf(p2 * p2);
    return fmaf(-au, r, xpa);
}
__device__ __forceinline__ float gelu_h(float x) { return 0.5f * gelu2(x); }

__device__ __forceinline__ short f2bf(float f) {      // RNE float->bf16
    unsigned u = __float_as_uint(f);
    u += 0x7FFFu + ((u >> 16) & 1u);
    return (short)(u >> 16);
}
__device__ __forceinline__ float bflo(unsigned u) { return __uint_as_float(u << 16); }
__device__ __forceinline__ float bfhi(unsigned u) { return __uint_as_float(u & 0xFFFF0000u); }

// ---------------- K1: [0..511] Pt/Qm/XW/Pb/Qb + rowstats ; [512..580] WCb/v/Wn2b ----------------
__global__ __launch_bounds__(256) void k_pre(const float* __restrict__ slots,
                                             const float* __restrict__ We1,
                                             const float* __restrict__ be1,
                                             const float* __restrict__ Wn1,
                                             const float* __restrict__ We2,
                                             const float* __restrict__ be2,
                                             const float* __restrict__ Wn2,
                                             float* __restrict__ Pt,
                                             float* __restrict__ Qm,
                                             float* __restrict__ XW,
                                             short* __restrict__ Pb,
                                             short* __restrict__ Qb,
                                             float4* __restrict__ rowstats,
                                             unsigned short* __restrict__ WCb,
                                             float* __restrict__ v,
                                             unsigned short* __restrict__ Wn2b) {
    __shared__ float xs[RP][ND];
    __shared__ float red[4][RP][4];
    const int t = threadIdx.x;

    if (blockIdx.x >= 512) {           // ---- prep role ----
        const int bid2 = blockIdx.x - 512;
        if (bid2 == 64) {              // v = be2 @ Wn1_bot
            __shared__ float bs[ND];
            if (t < ND) bs[t] = be2[t];
            __syncthreads();
            float acc = 0.f;
            #pragma unroll 4
            for (int d = 0; d < ND; ++d) acc = fmaf(bs[d], Wn1[(ND + d) * NH + t], acc);
            v[t] = acc;
            return;
        }
        if (bid2 > 64) {               // Wn2b = bf16(Wn2), same [256][128] layout
            const int base = (bid2 - 65) * 8192;
            #pragma unroll 8
            for (int i = 0; i < 32; ++i) {
                const int idx = base + i * 256 + t;
                Wn2b[idx] = (unsigned short)f2bf(Wn2[idx]);
            }
            return;
        }
        const int k0 = bid2 * 4;       // WCb rows k0..k0+3 (bf16)
        __shared__ float ws[4][ND];
        #pragma unroll
        for (int i = 0; i < 2; ++i) {
            const int idx = t + i * 256;
            ws[idx >> 7][idx & 127] = We2[(k0 + (idx >> 7)) * ND + (idx & 127)];
        }
        __syncthreads();
        float acc[4] = {0.f, 0.f, 0.f, 0.f};
        #pragma unroll 4
        for (int d = 0; d < ND; ++d) {
            const float wn = Wn1[(ND + d) * NH + t];
            #pragma unroll
            for (int r = 0; r < 4; ++r) acc[r] = fmaf(ws[r][d], wn, acc[r]);
        }
        #pragma unroll
        for (int r = 0; r < 4; ++r)
            WCb[(size_t)(k0 + r) * NH + t] = (unsigned short)f2bf(acc[r]);
        return;
    }

    // ---- pq role ----
    const int r0 = blockIdx.x * RP;
    const int lane = t & 63, wave = t >> 6;
    #pragma unroll
    for (int i = 0; i < 2; ++i) {
        const int idx = t + i * 256;
        xs[idx >> 7][idx & 127] = slots[(size_t)(r0 + (idx >> 7)) * ND + (idx & 127)];
    }
    __syncthreads();
    float pt[RP], qq[RP], xw[RP];
    const float bb = be1[t];
    #pragma unroll
    for (int r = 0; r < RP; ++r) { pt[r] = bb; qq[r] = 0.f; xw[r] = 0.f; }
    #pragma unroll 4
    for (int d = 0; d < ND; ++d) {
        const float wt  = We1[d * NH + t];
        const float wbt = We1[(ND + d) * NH + t];
        const float wn  = Wn1[d * NH + t];
        #pragma unroll
        for (int r = 0; r < RP; ++r) {
            const float x = xs[r][d];
            pt[r] = fmaf(x, wt,  pt[r]);
            qq[r] = fmaf(x, wbt, qq[r]);
            xw[r] = fmaf(x, wn,  xw[r]);
        }
    }
    #pragma unroll
    for (int r = 0; r < RP; ++r) {
        const size_t row = (size_t)(r0 + r);
        Pt[row * NH + t] = pt[r];
        Qm[row * NH + t] = qq[r];
        XW[row * NH + t] = xw[r];
        Pb[row * NH + t] = f2bf(pt[r]);
        Qb[row * NH + t] = f2bf(qq[r]);
    }
    float s1[RP], s2[RP], s3[RP], s4[RP];
    #pragma unroll
    for (int r = 0; r < RP; ++r) {
        s1[r] = pt[r]; s2[r] = pt[r] * pt[r];
        s3[r] = qq[r]; s4[r] = qq[r] * qq[r];
    }
    #pragma unroll
    for (int off = 32; off; off >>= 1) {
        #pragma unroll
        for (int r = 0; r < RP; ++r) {
            s1[r] += __shfl_xor(s1[r], off);
            s2[r] += __shfl_xor(s2[r], off);
            s3[r] += __shfl_xor(s3[r], off);
            s4[r] += __shfl_xor(s4[r], off);
        }
    }
    if (lane == 0) {
        #pragma unroll
        for (int r = 0; r < RP; ++r) {
            red[wave][r][0] = s1[r]; red[wave][r][1] = s2[r];
            red[wave][r][2] = s3[r]; red[wave][r][3] = s4[r];
        }
    }
    __syncthreads();
    if (t < RP) {
        float4 st;
        st.x = (red[0][t][0] + red[1][t][0]) + (red[2][t][0] + red[3][t][0]);
        st.y = (red[0][t][1] + red[1][t][1]) + (red[2][t][1] + red[3][t][1]);
        st.z = (red[0][t][2] + red[1][t][2]) + (red[2][t][2] + red[3][t][2]);
        st.w = (red[0][t][3] + red[1][t][3]) + (red[2][t][3] + red[3][t][3]);
        rowstats[r0 + t] = st;
    }
}

// ---------------- K2: MFMA dot -> wmr table {0.5w, rr, -mu*rr, w} ----------------
__global__ __launch_bounds__(256) void k_dot(
    const short* __restrict__ Pb, const short* __restrict__ Qb,
    const float4* __restrict__ rowstats,
    const float* __restrict__ adj,
    float4* __restrict__ wmrG)
{
    const int b  = blockIdx.x >> 2;
    const int jt = blockIdx.x & 3;
    const int t  = threadIdx.x;
    const int l  = t & 63;
    const int i0 = (t >> 6) * 16;
    const int j0 = jt * 16;
    const int rA = l & 15;
    const int kg = l >> 4;

    const short* Prow = Pb + ((size_t)b * NN + i0 + rA) * NH + kg * 8;
    const short* Qrow = Qb + ((size_t)b * NN + j0 + rA) * NH + kg * 8;
    f32x4 acc = {0.f, 0.f, 0.f, 0.f};
    #pragma unroll
    for (int kc = 0; kc < 8; ++kc) {
        const bf16x8 av = *(const bf16x8*)(Prow + kc * 32);
        const bf16x8 bv = *(const bf16x8*)(Qrow + kc * 32);
        acc = __builtin_amdgcn_mfma_f32_16x16x32_bf16(av, bv, acc, 0, 0, 0);
    }
    const int j  = j0 + rA;
    const int gj = b * NN + j;
    const float4 stj = rowstats[gj];
    const float inv = 1.0f / NH;
    #pragma unroll
    for (int q = 0; q < 4; ++q) {
        const int i  = i0 + kg * 4 + q;
        const int gi = b * NN + i;
        const float4 sti = rowstats[gi];
        float a = adj[(size_t)gi * NN + j];
        if (j == i) a = 0.f;
        const float cd = acc[q];
        const float mu = (sti.x + stj.z) * inv;
        const float e2 = fmaf(2.f, cd, sti.y + stj.w) * inv;
        const float rr = __builtin_amdgcn_rsqf(fmaf(-mu, mu, e2) + LN_EPS);
        wmrG[(size_t)gi * NN + j] = make_float4(0.5f * a, rr, -mu * rr, a);
    }
}

// ---------------- K3: fused msg+node, 2 rows/block, 512 threads, 1024 blocks (100% occ) ----------------
__global__ __launch_bounds__(512, 8) void k_mn(
    const float* __restrict__ slots,
    const float* __restrict__ Pt,
    const float* __restrict__ Qm,
    const float4* __restrict__ wmrG,
    const float* __restrict__ ge,  const float* __restrict__ bge,
    const float* __restrict__ XW,
    const unsigned short* __restrict__ WCb, const float* __restrict__ v,
    const float* __restrict__ bn1,
    const float* __restrict__ gn,  const float* __restrict__ bgn,
    const unsigned short* __restrict__ Wn2b, const float* __restrict__ bn2,
    float* __restrict__ out)
{
    union U {
        struct { float4 wmr[2][NN]; float s[8][NH]; } e;          // 2KB + 8KB
        struct { float sfg[2][NH];                                 // 2KB (overlays wmr)
                 union { float part[8][2][NH];                     // 16KB (overlays s)
                         float d[2][16][ND + 4]; } w; } n;         // 16.9KB
    };
    __shared__ U u;
    __shared__ float lds_ws[2];
    __shared__ float lds_red[8][2];
    __shared__ float lds_mr[2][2];

    const int row0 = blockIdx.x * 2;
    const int b    = row0 >> 6;
    const int t    = threadIdx.x;       // 0..511
    const int lane = t & 63;
    const int wave = t >> 6;            // 0..7
    const int half = t >> 8;            // row select (0/1)
    const int c    = t & 255;           // channel
    const int wih  = wave & 3;          // wave-in-half

    const int myrow = row0 + half;
    const float xw = XW[(size_t)myrow * NH + c];
    float sl = 0.f;
    if (t < 256) sl = slots[(size_t)(row0 + (t >> 7)) * ND + (t & 127)];
    if (t < 128) u.e.wmr[t >> 6][t & 63] = wmrG[(size_t)(row0 + (t >> 6)) * NN + (t & 63)];
    const float4 P  = ((const float4*)(Pt + (size_t)myrow * NH))[lane];
    const float4 G  = ((const float4*)ge)[lane];
    const float4 Bg = ((const float4*)bge)[lane];
    __syncthreads();                                   // bar1: wmr ready

    if (wave < 2) {                                    // wsum per row, off critical path
        float wv = u.e.wmr[wave][lane].w;
        #pragma unroll
        for (int off = 32; off; off >>= 1) wv += __shfl_xor(wv, off);
        if (lane == 0) lds_ws[wave] = wv;
    }

    // ---- edge main loop: each half owns its row; 4 waves per half ----
    const float4* Qb4 = (const float4*)(Qm + (size_t)b * NN * NH) + lane;
    float4 A = make_float4(0.f, 0.f, 0.f, 0.f);
    #pragma unroll 4
    for (int k = 0; k < 16; ++k) {
        const int jj = wih + 4 * k;
        const float4 q = Qb4[jj * (NH / 4)];
        const float4 m = u.e.wmr[half][jj];
        float h, uu;
        h = P.x + q.x; uu = fmaf(fmaf(h, m.y, m.z), G.x, Bg.x); A.x = fmaf(m.x, gelu2(uu), A.x);
        h = P.y + q.y; uu = fmaf(fmaf(h, m.y, m.z), G.y, Bg.y); A.y = fmaf(m.x, gelu2(uu), A.y);
        h = P.z + q.z; uu = fmaf(fmaf(h, m.y, m.z), G.z, Bg.z); A.z = fmaf(m.x, gelu2(uu), A.z);
        h = P.w + q.w; uu = fmaf(fmaf(h, m.y, m.z), G.w, Bg.w); A.w = fmaf(m.x, gelu2(uu), A.w);
    }
    ((float4*)u.e.s[wave])[lane] = A;
    __syncthreads();                                   // bar2: s ready; wmr dead

    // reduce 4 wave-partials of this half's row; write g-buffer region (overlays wmr)
    const float sf = (u.e.s[half * 4 + 0][c] + u.e.s[half * 4 + 1][c])
                   + (u.e.s[half * 4 + 2][c] + u.e.s[half * 4 + 3][c]);
    u.n.sfg[half][c] = sf;
    __syncthreads();                                   // bar3: sfg ready; s reads done

    // ---- WC GEMV: bf16 weights, 8-way k-split, both rows; weights loaded once/block ----
    {
        const int ks = wave;            // 0..7, 32 k each
        const int cg = lane;            // channels 4cg..4cg+3
        float4 h0 = make_float4(0.f, 0.f, 0.f, 0.f);
        float4 h1 = make_float4(0.f, 0.f, 0.f, 0.f);
        const uint2* wc2 = (const uint2*)WCb + cg;     // row = 64 uint2
        #pragma unroll 8
        for (int k = ks * 32; k < ks * 32 + 32; ++k) {
            const uint2 wp = wc2[k * 64];
            const float w0 = bflo(wp.x), w1 = bfhi(wp.x);
            const float w2v = bflo(wp.y), w3 = bfhi(wp.y);
            const float sa = u.n.sfg[0][k];
            const float sb = u.n.sfg[1][k];
            h0.x = fmaf(sa, w0, h0.x); h0.y = fmaf(sa, w1, h0.y);
            h0.z = fmaf(sa, w2v, h0.z); h0.w = fmaf(sa, w3, h0.w);
            h1.x = fmaf(sb, w0, h1.x); h1.y = fmaf(sb, w1, h1.y);
            h1.z = fmaf(sb, w2v, h1.z); h1.w = fmaf(sb, w3, h1.w);
        }
        ((float4*)u.n.w.part[ks][0])[cg] = h0;
        ((float4*)u.n.w.part[ks][1])[cg] = h1;
    }
    __syncthreads();                                   // bar4: part ready

    float a0;
    {
        const float b1 = bn1[c], vc = v[c];
        float sum = 0.f;
        #pragma unroll
        for (int p = 0; p < 8; ++p) sum += u.n.w.part[p][half][c];
        a0 = sum + fmaf(lds_ws[half], vc, b1) + xw;
    }
    {
        float s1 = a0, s2 = a0 * a0;
        #pragma unroll
        for (int off = 32; off; off >>= 1) {
            s1 += __shfl_xor(s1, off); s2 += __shfl_xor(s2, off);
        }
        if (lane == 0) { lds_red[wave][0] = s1; lds_red[wave][1] = s2; }
    }
    __syncthreads();                                   // bar5
    if (t < 2) {
        const float S1 = (lds_red[4 * t + 0][0] + lds_red[4 * t + 1][0])
                       + (lds_red[4 * t + 2][0] + lds_red[4 * t + 3][0]);
        const float S2 = (lds_red[4 * t + 0][1] + lds_red[4 * t + 1][1])
                       + (lds_red[4 * t + 2][1] + lds_red[4 * t + 3][1]);
        const float mu  = S1 * (1.0f / NH);
        const float var = fmaf(-mu, mu, S2 * (1.0f / NH));
        lds_mr[t][0] = mu;
        lds_mr[t][1] = __builtin_amdgcn_rsqf(var + LN_EPS);
    }
    __syncthreads();                                   // bar6
    {
        const float g = gn[c], bg = bgn[c];
        const float rr = lds_mr[half][1];
        u.n.sfg[half][c] = gelu_h(fmaf(fmaf(a0, rr, -lds_mr[half][0] * rr), g, bg));
    }
    __syncthreads();                                   // bar7: g ready

    // ---- delta = g @ Wn2 (bf16, 16-way k-split, both rows; d overlays part) ----
    {
        const int ks2 = t >> 5;         // 0..15, 16 k each
        const int cg2 = t & 31;         // channel group of 4
        float4 d0 = make_float4(0.f, 0.f, 0.f, 0.f);
        float4 d1 = make_float4(0.f, 0.f, 0.f, 0.f);
        const uint2* w2b = (const uint2*)Wn2b + cg2;   // row = 32 uint2
        #pragma unroll 8
        for (int k = ks2 * 16; k < ks2 * 16 + 16; ++k) {
            const uint2 wp = w2b[k * 32];
            const float w0 = bflo(wp.x), w1 = bfhi(wp.x);
            const float w2v = bflo(wp.y), w3 = bfhi(wp.y);
            const float g0 = u.n.sfg[0][k];
            const float g1 = u.n.sfg[1][k];
            d0.x = fmaf(g0, w0, d0.x); d0.y = fmaf(g0, w1, d0.y);
            d0.z = fmaf(g0, w2v, d0.z); d0.w = fmaf(g0, w3, d0.w);
            d1.x = fmaf(g1, w0, d1.x); d1.y = fmaf(g1, w1, d1.y);
            d1.z = fmaf(g1, w2v, d1.z); d1.w = fmaf(g1, w3, d1.w);
        }
        ((float4*)u.n.w.d[0][ks2])[cg2] = d0;
        ((float4*)u.n.w.d[1][ks2])[cg2] = d1;
    }
    __syncthreads();                                   // bar8: d ready
    if (t < 256) {
        const int r  = t >> 7;
        const int c2 = t & 127;
        float ds = 0.f;
        #pragma unroll
        for (int p = 0; p < 16; ++p) ds += u.n.w.d[r][p][c2];
        out[(size_t)(row0 + r) * ND + c2] = sl + bn2[c2] + ds;
    }
}

extern "C" void kernel_launch(void* const* d_in, const int* in_sizes, int n_in,
                              void* d_out, int out_size, void* d_ws, size_t ws_size,
                              hipStream_t stream) {
    const float* slots = (const float*)d_in[0];
    const float* adj   = (const float*)d_in[1];
    const float* We1   = (const float*)d_in[2];
    const float* be1   = (const float*)d_in[3];
    const float* ge    = (const float*)d_in[4];
    const float* bge   = (const float*)d_in[5];
    const float* We2   = (const float*)d_in[6];
    const float* be2   = (const float*)d_in[7];
    const float* Wn1   = (const float*)d_in[8];
    const float* bn1   = (const float*)d_in[9];
    const float* gn    = (const float*)d_in[10];
    const float* bgn   = (const float*)d_in[11];
    const float* Wn2   = (const float*)d_in[12];
    const float* bn2   = (const float*)d_in[13];
    float* out = (float*)d_out;

    const size_t RN = (size_t)NB * NN;          // 2048
    float*  Ptw  = (float*)d_ws;                // [2048,256] f32
    float*  Qw   = Ptw  + RN * NH;              // [2048,256] f32
    float*  XWw  = Qw   + RN * NH;              // [2048,256] f32
    float*  vw   = XWw  + RN * NH;              // [256]
    float4* rsw  = (float4*)(vw + NH + 768);    // [2048] (16B aligned: 256+768=1024 floats)
    float4* wmrw = rsw + RN;                    // [2048*64]
    short*  Pbw  = (short*)(wmrw + RN * NN);    // [2048,256] bf16
    short*  Qbw  = Pbw + RN * NH;               // [2048,256] bf16
    unsigned short* WCbw  = (unsigned short*)(Qbw + RN * NH);   // [256,256] bf16
    unsigned short* Wn2bw = WCbw + (size_t)NH * NH;             // [256,128] bf16

    k_pre<<<581,            256, 0, stream>>>(slots, We1, be1, Wn1, We2, be2, Wn2,
                                              Ptw, Qw, XWw, Pbw, Qbw, rsw, WCbw, vw, Wn2bw);
    k_dot<<<NB * 4,         256, 0, stream>>>(Pbw, Qbw, rsw, adj, wmrw);
    k_mn <<<(int)(RN / 2),  512, 0, stream>>>(slots, Ptw, Qw, wmrw, ge, bge,
                                              XWw, WCbw, vw, bn1, gn, bgn, Wn2bw, bn2, out);
}

// Round 18
// 59.325 us; speedup vs baseline: 1.0065x; 1.0065x over previous
//
#include <hip/hip_runtime.h>

#define NB 32
#define NN 64
#define ND 128
#define NH 256
#define LN_EPS 1e-5f
#define RP 4

typedef __attribute__((ext_vector_type(8))) short bf16x8;
typedef __attribute__((ext_vector_type(4))) float f32x4;

// ---- branchless erf-based GELU, A&S 7.1.25 (|erf err| <= 5e-4), Estrin form ----
__device__ __forceinline__ float gelu2(float x) {     // returns 2*gelu(x)
    const float au  = fabsf(x);
    const float xpa = x + au;
    const float z   = au * 0.70710678118654752440f;
    const float z2  = z * z;
    const float pc  = fmaf(0.078108f, z, 0.000972f);
    const float pb  = fmaf(0.278393f, z, 1.0f);
    const float p   = fmaf(z2, fmaf(z, pc, 0.230389f), pb);
    const float p2  = p * p;
    const float r   = __builtin_amdgcn_rcpf(p2 * p2);
    return fmaf(-au, r, xpa);
}
__device__ __forceinline__ float gelu_h(float x) { return 0.5f * gelu2(x); }

__device__ __forceinline__ short f2bf(float f) {      // RNE float->bf16
    unsigned u = __float_as_uint(f);
    u += 0x7FFFu + ((u >> 16) & 1u);
    return (short)(u >> 16);
}
__device__ __forceinline__ float bflo(unsigned u) { return __uint_as_float(u << 16); }
__device__ __forceinline__ float bfhi(unsigned u) { return __uint_as_float(u & 0xFFFF0000u); }

// ---------------- K1: [0..511] Pt/Qm/XW/Pb/Qb + rowstats (512t, d-split) ; [512..580] prep ----------------
__global__ __launch_bounds__(512) void k_pre(const float* __restrict__ slots,
                                             const float* __restrict__ We1,
                                             const float* __restrict__ be1,
                                             const float* __restrict__ Wn1,
                                             const float* __restrict__ We2,
                                             const float* __restrict__ be2,
                                             const float* __restrict__ Wn2,
                                             float* __restrict__ Pt,
                                             float* __restrict__ Qm,
                                             float* __restrict__ XW,
                                             short* __restrict__ Pb,
                                             short* __restrict__ Qb,
                                             float4* __restrict__ rowstats,
                                             unsigned short* __restrict__ WCb,
                                             float* __restrict__ v,
                                             unsigned short* __restrict__ Wn2b) {
    const int t = threadIdx.x;         // 0..511

    if (blockIdx.x >= 512) {           // ---- prep role ----
        const int bid2 = blockIdx.x - 512;
        if (bid2 == 64) {              // v = be2 @ Wn1_bot
            __shared__ float bs[ND];
            if (t < ND) bs[t] = be2[t];
            __syncthreads();
            if (t < 256) {
                float acc = 0.f;
                #pragma unroll 4
                for (int d = 0; d < ND; ++d) acc = fmaf(bs[d], Wn1[(ND + d) * NH + t], acc);
                v[t] = acc;
            }
            return;
        }
        if (bid2 > 64) {               // Wn2b = bf16(Wn2), same [256][128] layout
            const int base = (bid2 - 65) * 8192;
            #pragma unroll 4
            for (int i = 0; i < 16; ++i) {
                const int idx = base + i * 512 + t;
                Wn2b[idx] = (unsigned short)f2bf(Wn2[idx]);
            }
            return;
        }
        const int k0 = bid2 * 4;       // WCb rows k0..k0+3 (bf16)
        __shared__ float ws[4][ND];
        ws[t >> 7][t & 127] = We2[(k0 + (t >> 7)) * ND + (t & 127)];
        __syncthreads();
        if (t < 256) {
            float acc[4] = {0.f, 0.f, 0.f, 0.f};
            #pragma unroll 4
            for (int d = 0; d < ND; ++d) {
                const float wn = Wn1[(ND + d) * NH + t];
                #pragma unroll
                for (int r = 0; r < 4; ++r) acc[r] = fmaf(ws[r][d], wn, acc[r]);
            }
            #pragma unroll
            for (int r = 0; r < 4; ++r)
                WCb[(size_t)(k0 + r) * NH + t] = (unsigned short)f2bf(acc[r]);
        }
        return;
    }

    // ---- pq role: 512 threads, d-split halves ----
    __shared__ float xs[RP][ND];              // 2KB
    __shared__ float part[2][3][RP][256];     // 24KB
    __shared__ float red[4][RP][4];

    const int r0 = blockIdx.x * RP;
    const int c  = t & 255;
    const int dh = t >> 8;                    // d-half 0/1

    xs[t >> 7][t & 127] = slots[(size_t)(r0 + (t >> 7)) * ND + (t & 127)];
    __syncthreads();

    float pt[RP], qq[RP], xw[RP];
    #pragma unroll
    for (int r = 0; r < RP; ++r) { pt[r] = 0.f; qq[r] = 0.f; xw[r] = 0.f; }
    const int d0 = dh * 64;
    #pragma unroll 4
    for (int dd = 0; dd < 64; ++dd) {
        const int d = d0 + dd;
        const float wt  = We1[d * NH + c];
        const float wbt = We1[(ND + d) * NH + c];
        const float wn  = Wn1[d * NH + c];
        #pragma unroll
        for (int r = 0; r < RP; ++r) {
            const float x = xs[r][d];
            pt[r] = fmaf(x, wt,  pt[r]);
            qq[r] = fmaf(x, wbt, qq[r]);
            xw[r] = fmaf(x, wn,  xw[r]);
        }
    }
    #pragma unroll
    for (int r = 0; r < RP; ++r) {
        part[dh][0][r][c] = pt[r];
        part[dh][1][r][c] = qq[r];
        part[dh][2][r][c] = xw[r];
    }
    __syncthreads();

    // combine + store; each (m,r,c) owned by exactly one thread
    #pragma unroll
    for (int i = t; i < 3 * RP * 256; i += 512) {
        const int m  = i >> 10;        // 0..2
        const int r  = (i >> 8) & 3;
        const int cc = i & 255;
        float val = part[0][m][r][cc] + part[1][m][r][cc];
        const size_t row = (size_t)(r0 + r);
        if (m == 0) {
            val += be1[cc];
            Pt[row * NH + cc] = val;
            Pb[row * NH + cc] = f2bf(val);
            part[0][0][r][cc] = val;   // combined P for stats
        } else if (m == 1) {
            Qm[row * NH + cc] = val;
            Qb[row * NH + cc] = f2bf(val);
            part[0][1][r][cc] = val;   // combined Q for stats
        } else {
            XW[row * NH + cc] = val;
        }
    }
    __syncthreads();

    if (t < 256) {
        const int lane = t & 63, wave = t >> 6;
        float s1[RP], s2[RP], s3[RP], s4[RP];
        #pragma unroll
        for (int r = 0; r < RP; ++r) {
            const float pv = part[0][0][r][t];
            const float qv = part[0][1][r][t];
            s1[r] = pv; s2[r] = pv * pv;
            s3[r] = qv; s4[r] = qv * qv;
        }
        #pragma unroll
        for (int off = 32; off; off >>= 1) {
            #pragma unroll
            for (int r = 0; r < RP; ++r) {
                s1[r] += __shfl_xor(s1[r], off);
                s2[r] += __shfl_xor(s2[r], off);
                s3[r] += __shfl_xor(s3[r], off);
                s4[r] += __shfl_xor(s4[r], off);
            }
        }
        if (lane == 0) {
            #pragma unroll
            for (int r = 0; r < RP; ++r) {
                red[wave][r][0] = s1[r]; red[wave][r][1] = s2[r];
                red[wave][r][2] = s3[r]; red[wave][r][3] = s4[r];
            }
        }
    }
    __syncthreads();
    if (t < RP) {
        float4 st;
        st.x = (red[0][t][0] + red[1][t][0]) + (red[2][t][0] + red[3][t][0]);
        st.y = (red[0][t][1] + red[1][t][1]) + (red[2][t][1] + red[3][t][1]);
        st.z = (red[0][t][2] + red[1][t][2]) + (red[2][t][2] + red[3][t][2]);
        st.w = (red[0][t][3] + red[1][t][3]) + (red[2][t][3] + red[3][t][3]);
        rowstats[r0 + t] = st;
    }
}

// ---------------- K2: MFMA dot -> wmr table {0.5w, rr, -mu*rr, w} ----------------
__global__ __launch_bounds__(256) void k_dot(
    const short* __restrict__ Pb, const short* __restrict__ Qb,
    const float4* __restrict__ rowstats,
    const float* __restrict__ adj,
    float4* __restrict__ wmrG)
{
    const int b  = blockIdx.x >> 2;
    const int jt = blockIdx.x & 3;
    const int t  = threadIdx.x;
    const int l  = t & 63;
    const int i0 = (t >> 6) * 16;
    const int j0 = jt * 16;
    const int rA = l & 15;
    const int kg = l >> 4;

    const short* Prow = Pb + ((size_t)b * NN + i0 + rA) * NH + kg * 8;
    const short* Qrow = Qb + ((size_t)b * NN + j0 + rA) * NH + kg * 8;
    f32x4 acc = {0.f, 0.f, 0.f, 0.f};
    #pragma unroll
    for (int kc = 0; kc < 8; ++kc) {
        const bf16x8 av = *(const bf16x8*)(Prow + kc * 32);
        const bf16x8 bv = *(const bf16x8*)(Qrow + kc * 32);
        acc = __builtin_amdgcn_mfma_f32_16x16x32_bf16(av, bv, acc, 0, 0, 0);
    }
    const int j  = j0 + rA;
    const int gj = b * NN + j;
    const float4 stj = rowstats[gj];
    const float inv = 1.0f / NH;
    #pragma unroll
    for (int q = 0; q < 4; ++q) {
        const int i  = i0 + kg * 4 + q;
        const int gi = b * NN + i;
        const float4 sti = rowstats[gi];
        float a = adj[(size_t)gi * NN + j];
        if (j == i) a = 0.f;
        const float cd = acc[q];
        const float mu = (sti.x + stj.z) * inv;
        const float e2 = fmaf(2.f, cd, sti.y + stj.w) * inv;
        const float rr = __builtin_amdgcn_rsqf(fmaf(-mu, mu, e2) + LN_EPS);
        wmrG[(size_t)gi * NN + j] = make_float4(0.5f * a, rr, -mu * rr, a);
    }
}

// ---------------- K3: fused msg+node, 2 rows/block, 1024 blocks (R13-verbatim) ----------------
__global__ __launch_bounds__(256, 4) void k_mn(
    const float* __restrict__ slots,
    const float* __restrict__ Pt,
    const float* __restrict__ Qm,
    const float4* __restrict__ wmrG,
    const float* __restrict__ ge,  const float* __restrict__ bge,
    const float* __restrict__ XW,
    const unsigned short* __restrict__ WCb, const float* __restrict__ v,
    const float* __restrict__ bn1,
    const float* __restrict__ gn,  const float* __restrict__ bgn,
    const unsigned short* __restrict__ Wn2b, const float* __restrict__ bn2,
    float* __restrict__ out)
{
    union U {
        struct { float4 wmr[2][NN]; float s[4][2][NH]; } e;
        struct { float sfg[2][NH];
                 union { float part[2][4][NH]; float d[2][8][ND + 4]; } w; } n;
    };
    __shared__ U u;
    __shared__ float lds_ws[2];
    __shared__ float lds_red[4][2][2];
    __shared__ float lds_mr[2][2];

    const int row0 = blockIdx.x * 2;
    const int b    = row0 >> 6;
    const int t    = threadIdx.x;
    const int lane = t & 63;
    const int wave = t >> 6;

    const float xw0 = XW[(size_t)row0 * NH + t];
    const float xw1 = XW[(size_t)(row0 + 1) * NH + t];
    const float sl  = slots[(size_t)(row0 + (t >> 7)) * ND + (t & 127)];
    if (t < 128) {
        const int r = t >> 6, j = t & 63;
        u.e.wmr[r][j] = wmrG[(size_t)(row0 + r) * NN + j];
    }
    const float4 P0 = ((const float4*)(Pt + (size_t)row0 * NH))[lane];
    const float4 P1 = ((const float4*)(Pt + (size_t)(row0 + 1) * NH))[lane];
    const float4 G  = ((const float4*)ge)[lane];
    const float4 Bg = ((const float4*)bge)[lane];
    __syncthreads();

    if (wave < 2) {
        float wv = u.e.wmr[wave][lane].w;
        #pragma unroll
        for (int off = 32; off; off >>= 1) wv += __shfl_xor(wv, off);
        if (lane == 0) lds_ws[wave] = wv;
    }

    const float4* Qb4 = (const float4*)(Qm + (size_t)b * NN * NH) + lane;
    float4 A0 = make_float4(0.f, 0.f, 0.f, 0.f);
    float4 A1 = make_float4(0.f, 0.f, 0.f, 0.f);
    #pragma unroll 4
    for (int k = 0; k < 16; ++k) {
        const int jj = wave + 4 * k;
        const float4 q  = Qb4[jj * (NH / 4)];
        const float4 m0 = u.e.wmr[0][jj];
        const float4 m1 = u.e.wmr[1][jj];
        float h, uu;
        h = P0.x + q.x; uu = fmaf(fmaf(h, m0.y, m0.z), G.x, Bg.x); A0.x = fmaf(m0.x, gelu2(uu), A0.x);
        h = P0.y + q.y; uu = fmaf(fmaf(h, m0.y, m0.z), G.y, Bg.y); A0.y = fmaf(m0.x, gelu2(uu), A0.y);
        h = P0.z + q.z; uu = fmaf(fmaf(h, m0.y, m0.z), G.z, Bg.z); A0.z = fmaf(m0.x, gelu2(uu), A0.z);
        h = P0.w + q.w; uu = fmaf(fmaf(h, m0.y, m0.z), G.w, Bg.w); A0.w = fmaf(m0.x, gelu2(uu), A0.w);
        h = P1.x + q.x; uu = fmaf(fmaf(h, m1.y, m1.z), G.x, Bg.x); A1.x = fmaf(m1.x, gelu2(uu), A1.x);
        h = P1.y + q.y; uu = fmaf(fmaf(h, m1.y, m1.z), G.y, Bg.y); A1.y = fmaf(m1.x, gelu2(uu), A1.y);
        h = P1.z + q.z; uu = fmaf(fmaf(h, m1.y, m1.z), G.z, Bg.z); A1.z = fmaf(m1.x, gelu2(uu), A1.z);
        h = P1.w + q.w; uu = fmaf(fmaf(h, m1.y, m1.z), G.w, Bg.w); A1.w = fmaf(m1.x, gelu2(uu), A1.w);
    }
    ((float4*)u.e.s[wave][0])[lane] = A0;
    ((float4*)u.e.s[wave][1])[lane] = A1;
    __syncthreads();

    const float sf0 = (u.e.s[0][0][t] + u.e.s[1][0][t]) + (u.e.s[2][0][t] + u.e.s[3][0][t]);
    const float sf1 = (u.e.s[0][1][t] + u.e.s[1][1][t]) + (u.e.s[2][1][t] + u.e.s[3][1][t]);
    __syncthreads();
    u.n.sfg[0][t] = sf0;
    u.n.sfg[1][t] = sf1;
    __syncthreads();

    // ---- WC GEMV: bf16 weights, 4-way k-split ----
    {
        const int ks = wave;
        const int cg = lane;
        float4 h0 = make_float4(0.f, 0.f, 0.f, 0.f);
        float4 h1 = make_float4(0.f, 0.f, 0.f, 0.f);
        const uint2* wc2 = (const uint2*)WCb + cg;     // row = 64 uint2
        #pragma unroll 8
        for (int k = ks * 64; k < ks * 64 + 64; ++k) {
            const uint2 wp = wc2[k * 64];
            const float w0 = bflo(wp.x), w1 = bfhi(wp.x);
            const float w2v = bflo(wp.y), w3 = bfhi(wp.y);
            const float sa = u.n.sfg[0][k];
            const float sb = u.n.sfg[1][k];
            h0.x = fmaf(sa, w0, h0.x); h0.y = fmaf(sa, w1, h0.y);
            h0.z = fmaf(sa, w2v, h0.z); h0.w = fmaf(sa, w3, h0.w);
            h1.x = fmaf(sb, w0, h1.x); h1.y = fmaf(sb, w1, h1.y);
            h1.z = fmaf(sb, w2v, h1.z); h1.w = fmaf(sb, w3, h1.w);
        }
        ((float4*)u.n.w.part[0][ks])[cg] = h0;
        ((float4*)u.n.w.part[1][ks])[cg] = h1;
    }
    __syncthreads();

    float a0, a1;
    {
        const float b1 = bn1[t], vc = v[t];
        a0 = (u.n.w.part[0][0][t] + u.n.w.part[0][1][t])
           + (u.n.w.part[0][2][t] + u.n.w.part[0][3][t])
           + fmaf(lds_ws[0], vc, b1) + xw0;
        a1 = (u.n.w.part[1][0][t] + u.n.w.part[1][1][t])
           + (u.n.w.part[1][2][t] + u.n.w.part[1][3][t])
           + fmaf(lds_ws[1], vc, b1) + xw1;
    }
    {
        float s1 = a0, s2 = a0 * a0, s3 = a1, s4 = a1 * a1;
        #pragma unroll
        for (int off = 32; off; off >>= 1) {
            s1 += __shfl_xor(s1, off); s2 += __shfl_xor(s2, off);
            s3 += __shfl_xor(s3, off); s4 += __shfl_xor(s4, off);
        }
        if (lane == 0) {
            lds_red[wave][0][0] = s1; lds_red[wave][0][1] = s2;
            lds_red[wave][1][0] = s3; lds_red[wave][1][1] = s4;
        }
    }
    __syncthreads();
    if (t < 2) {
        const float S1 = (lds_red[0][t][0] + lds_red[1][t][0]) + (lds_red[2][t][0] + lds_red[3][t][0]);
        const float S2 = (lds_red[0][t][1] + lds_red[1][t][1]) + (lds_red[2][t][1] + lds_red[3][t][1]);
        const float mu  = S1 * (1.0f / NH);
        const float var = fmaf(-mu, mu, S2 * (1.0f / NH));
        lds_mr[t][0] = mu;
        lds_mr[t][1] = __builtin_amdgcn_rsqf(var + LN_EPS);
    }
    __syncthreads();
    {
        const float g = gn[t], bg = bgn[t];
        const float rr0 = lds_mr[0][1], rr1 = lds_mr[1][1];
        u.n.sfg[0][t] = gelu_h(fmaf(fmaf(a0, rr0, -lds_mr[0][0] * rr0), g, bg));
        u.n.sfg[1][t] = gelu_h(fmaf(fmaf(a1, rr1, -lds_mr[1][0] * rr1), g, bg));
    }
    __syncthreads();

    // ---- delta = g @ Wn2 (bf16 weights, 8-way k-split, both rows) ----
    {
        const int ks = t >> 5;
        const int cg = t & 31;
        float4 d0 = make_float4(0.f, 0.f, 0.f, 0.f);
        float4 d1 = make_float4(0.f, 0.f, 0.f, 0.f);
        const uint2* w2b = (const uint2*)Wn2b + cg;    // row = 32 uint2
        const int kbeg = ks * 32;
        #pragma unroll 8
        for (int k = kbeg; k < kbeg + 32; ++k) {
            const uint2 wp = w2b[k * 32];
            const float w0 = bflo(wp.x), w1 = bfhi(wp.x);
            const float w2v = bflo(wp.y), w3 = bfhi(wp.y);
            const float g0 = u.n.sfg[0][k];
            const float g1 = u.n.sfg[1][k];
            d0.x = fmaf(g0, w0, d0.x); d0.y = fmaf(g0, w1, d0.y);
            d0.z = fmaf(g0, w2v, d0.z); d0.w = fmaf(g0, w3, d0.w);
            d1.x = fmaf(g1, w0, d1.x); d1.y = fmaf(g1, w1, d1.y);
            d1.z = fmaf(g1, w2v, d1.z); d1.w = fmaf(g1, w3, d1.w);
        }
        ((float4*)u.n.w.d[0][ks])[cg] = d0;
        ((float4*)u.n.w.d[1][ks])[cg] = d1;
    }
    __syncthreads();
    {
        const int r  = t >> 7;
        const int c2 = t & 127;
        float ds = 0.f;
        #pragma unroll
        for (int p2 = 0; p2 < 8; ++p2) ds += u.n.w.d[r][p2][c2];
        out[(size_t)(row0 + r) * ND + c2] = sl + bn2[c2] + ds;
    }
}

extern "C" void kernel_launch(void* const* d_in, const int* in_sizes, int n_in,
                              void* d_out, int out_size, void* d_ws, size_t ws_size,
                              hipStream_t stream) {
    const float* slots = (const float*)d_in[0];
    const float* adj   = (const float*)d_in[1];
    const float* We1   = (const float*)d_in[2];
    const float* be1   = (const float*)d_in[3];
    const float* ge    = (const float*)d_in[4];
    const float* bge   = (const float*)d_in[5];
    const float* We2   = (const float*)d_in[6];
    const float* be2   = (const float*)d_in[7];
    const float* Wn1   = (const float*)d_in[8];
    const float* bn1   = (const float*)d_in[9];
    const float* gn    = (const float*)d_in[10];
    const float* bgn   = (const float*)d_in[11];
    const float* Wn2   = (const float*)d_in[12];
    const float* bn2   = (const float*)d_in[13];
    float* out = (float*)d_out;

    const size_t RN = (size_t)NB * NN;          // 2048
    float*  Ptw  = (float*)d_ws;                // [2048,256] f32
    float*  Qw   = Ptw  + RN * NH;              // [2048,256] f32
    float*  XWw  = Qw   + RN * NH;              // [2048,256] f32
    float*  vw   = XWw  + RN * NH;              // [256]
    float4* rsw  = (float4*)(vw + NH + 768);    // [2048] (16B aligned: 256+768=1024 floats)
    float4* wmrw = rsw + RN;                    // [2048*64]
    short*  Pbw  = (short*)(wmrw + RN * NN);    // [2048,256] bf16
    short*  Qbw  = Pbw + RN * NH;               // [2048,256] bf16
    unsigned short* WCbw  = (unsigned short*)(Qbw + RN * NH);   // [256,256] bf16
    unsigned short* Wn2bw = WCbw + (size_t)NH * NH;             // [256,128] bf16

    k_pre<<<581,            512, 0, stream>>>(slots, We1, be1, Wn1, We2, be2, Wn2,
                                              Ptw, Qw, XWw, Pbw, Qbw, rsw, WCbw, vw, Wn2bw);
    k_dot<<<NB * 4,         256, 0, stream>>>(Pbw, Qbw, rsw, adj, wmrw);
    k_mn <<<(int)(RN / 2),  256, 0, stream>>>(slots, Ptw, Qw, wmrw, ge, bge,
                                              XWw, WCbw, vw, bn1, gn, bgn, Wn2bw, bn2, out);
}

// Round 19
// 53.678 us; speedup vs baseline: 1.1124x; 1.1052x over previous
//
#include <hip/hip_runtime.h>

#define NB 32
#define NN 64
#define ND 128
#define NH 256
#define LN_EPS 1e-5f
#define RP 4

typedef __attribute__((ext_vector_type(8))) short bf16x8;
typedef __attribute__((ext_vector_type(4))) float f32x4;
typedef __attribute__((ext_vector_type(2))) float f32x2;

// ---- branchless erf-based GELU, A&S 7.1.25 (|erf err| <= 5e-4), Estrin form ----
__device__ __forceinline__ float gelu2(float x) {     // returns 2*gelu(x)
    const float au  = fabsf(x);
    const float xpa = x + au;
    const float z   = au * 0.70710678118654752440f;
    const float z2  = z * z;
    const float pc  = fmaf(0.078108f, z, 0.000972f);
    const float pb  = fmaf(0.278393f, z, 1.0f);
    const float p   = fmaf(z2, fmaf(z, pc, 0.230389f), pb);
    const float p2  = p * p;
    const float r   = __builtin_amdgcn_rcpf(p2 * p2);
    return fmaf(-au, r, xpa);
}
__device__ __forceinline__ float gelu_h(float x) { return 0.5f * gelu2(x); }

// packed 2-lane gelu2: all VALU ops on <2 x float> -> v_pk_* ; rcp stays scalar (trans)
__device__ __forceinline__ f32x2 gelu2v(f32x2 x) {
    const f32x2 au  = __builtin_elementwise_abs(x);
    const f32x2 xpa = x + au;
    const f32x2 z   = au * 0.70710678118654752440f;
    const f32x2 z2  = z * z;
    const f32x2 pc  = z * 0.078108f + 0.000972f;
    const f32x2 pb  = z * 0.278393f + 1.0f;
    const f32x2 p   = z2 * (z * pc + 0.230389f) + pb;
    const f32x2 p2  = p * p;
    const f32x2 p4  = p2 * p2;
    f32x2 r;
    r.x = __builtin_amdgcn_rcpf(p4.x);
    r.y = __builtin_amdgcn_rcpf(p4.y);
    return xpa - au * r;
}

__device__ __forceinline__ short f2bf(float f) {      // RNE float->bf16
    unsigned u = __float_as_uint(f);
    u += 0x7FFFu + ((u >> 16) & 1u);
    return (short)(u >> 16);
}
__device__ __forceinline__ float bflo(unsigned u) { return __uint_as_float(u << 16); }
__device__ __forceinline__ float bfhi(unsigned u) { return __uint_as_float(u & 0xFFFF0000u); }

// ---------------- K1: [0..511] Pt/Qm/XW/Pb/Qb + rowstats ; [512..580] WCb/v/Wn2b ----------------
__global__ __launch_bounds__(256) void k_pre(const float* __restrict__ slots,
                                             const float* __restrict__ We1,
                                             const float* __restrict__ be1,
                                             const float* __restrict__ Wn1,
                                             const float* __restrict__ We2,
                                             const float* __restrict__ be2,
                                             const float* __restrict__ Wn2,
                                             float* __restrict__ Pt,
                                             float* __restrict__ Qm,
                                             float* __restrict__ XW,
                                             short* __restrict__ Pb,
                                             short* __restrict__ Qb,
                                             float4* __restrict__ rowstats,
                                             unsigned short* __restrict__ WCb,
                                             float* __restrict__ v,
                                             unsigned short* __restrict__ Wn2b) {
    __shared__ float xs[RP][ND];
    __shared__ float red[4][RP][4];
    const int t = threadIdx.x;

    if (blockIdx.x >= 512) {           // ---- prep role ----
        const int bid2 = blockIdx.x - 512;
        if (bid2 == 64) {              // v = be2 @ Wn1_bot
            __shared__ float bs[ND];
            if (t < ND) bs[t] = be2[t];
            __syncthreads();
            float acc = 0.f;
            #pragma unroll 4
            for (int d = 0; d < ND; ++d) acc = fmaf(bs[d], Wn1[(ND + d) * NH + t], acc);
            v[t] = acc;
            return;
        }
        if (bid2 > 64) {               // Wn2b = bf16(Wn2), same [256][128] layout
            const int base = (bid2 - 65) * 8192;
            #pragma unroll 8
            for (int i = 0; i < 32; ++i) {
                const int idx = base + i * 256 + t;
                Wn2b[idx] = (unsigned short)f2bf(Wn2[idx]);
            }
            return;
        }
        const int k0 = bid2 * 4;       // WCb rows k0..k0+3 (bf16)
        __shared__ float ws[4][ND];
        #pragma unroll
        for (int i = 0; i < 2; ++i) {
            const int idx = t + i * 256;
            ws[idx >> 7][idx & 127] = We2[(k0 + (idx >> 7)) * ND + (idx & 127)];
        }
        __syncthreads();
        float acc[4] = {0.f, 0.f, 0.f, 0.f};
        #pragma unroll 4
        for (int d = 0; d < ND; ++d) {
            const float wn = Wn1[(ND + d) * NH + t];
            #pragma unroll
            for (int r = 0; r < 4; ++r) acc[r] = fmaf(ws[r][d], wn, acc[r]);
        }
        #pragma unroll
        for (int r = 0; r < 4; ++r)
            WCb[(size_t)(k0 + r) * NH + t] = (unsigned short)f2bf(acc[r]);
        return;
    }

    // ---- pq role ----
    const int r0 = blockIdx.x * RP;
    const int lane = t & 63, wave = t >> 6;
    #pragma unroll
    for (int i = 0; i < 2; ++i) {
        const int idx = t + i * 256;
        xs[idx >> 7][idx & 127] = slots[(size_t)(r0 + (idx >> 7)) * ND + (idx & 127)];
    }
    __syncthreads();
    float pt[RP], qq[RP], xw[RP];
    const float bb = be1[t];
    #pragma unroll
    for (int r = 0; r < RP; ++r) { pt[r] = bb; qq[r] = 0.f; xw[r] = 0.f; }
    #pragma unroll 4
    for (int d = 0; d < ND; ++d) {
        const float wt  = We1[d * NH + t];
        const float wbt = We1[(ND + d) * NH + t];
        const float wn  = Wn1[d * NH + t];
        #pragma unroll
        for (int r = 0; r < RP; ++r) {
            const float x = xs[r][d];
            pt[r] = fmaf(x, wt,  pt[r]);
            qq[r] = fmaf(x, wbt, qq[r]);
            xw[r] = fmaf(x, wn,  xw[r]);
        }
    }
    #pragma unroll
    for (int r = 0; r < RP; ++r) {
        const size_t row = (size_t)(r0 + r);
        Pt[row * NH + t] = pt[r];
        Qm[row * NH + t] = qq[r];
        XW[row * NH + t] = xw[r];
        Pb[row * NH + t] = f2bf(pt[r]);
        Qb[row * NH + t] = f2bf(qq[r]);
    }
    float s1[RP], s2[RP], s3[RP], s4[RP];
    #pragma unroll
    for (int r = 0; r < RP; ++r) {
        s1[r] = pt[r]; s2[r] = pt[r] * pt[r];
        s3[r] = qq[r]; s4[r] = qq[r] * qq[r];
    }
    #pragma unroll
    for (int off = 32; off; off >>= 1) {
        #pragma unroll
        for (int r = 0; r < RP; ++r) {
            s1[r] += __shfl_xor(s1[r], off);
            s2[r] += __shfl_xor(s2[r], off);
            s3[r] += __shfl_xor(s3[r], off);
            s4[r] += __shfl_xor(s4[r], off);
        }
    }
    if (lane == 0) {
        #pragma unroll
        for (int r = 0; r < RP; ++r) {
            red[wave][r][0] = s1[r]; red[wave][r][1] = s2[r];
            red[wave][r][2] = s3[r]; red[wave][r][3] = s4[r];
        }
    }
    __syncthreads();
    if (t < RP) {
        float4 st;
        st.x = (red[0][t][0] + red[1][t][0]) + (red[2][t][0] + red[3][t][0]);
        st.y = (red[0][t][1] + red[1][t][1]) + (red[2][t][1] + red[3][t][1]);
        st.z = (red[0][t][2] + red[1][t][2]) + (red[2][t][2] + red[3][t][2]);
        st.w = (red[0][t][3] + red[1][t][3]) + (red[2][t][3] + red[3][t][3]);
        rowstats[r0 + t] = st;
    }
}

// ---------------- K2: MFMA dot -> wmr table {0.5w, rr, -mu*rr, w} ----------------
__global__ __launch_bounds__(256) void k_dot(
    const short* __restrict__ Pb, const short* __restrict__ Qb,
    const float4* __restrict__ rowstats,
    const float* __restrict__ adj,
    float4* __restrict__ wmrG)
{
    const int b  = blockIdx.x >> 2;
    const int jt = blockIdx.x & 3;
    const int t  = threadIdx.x;
    const int l  = t & 63;
    const int i0 = (t >> 6) * 16;
    const int j0 = jt * 16;
    const int rA = l & 15;
    const int kg = l >> 4;

    const short* Prow = Pb + ((size_t)b * NN + i0 + rA) * NH + kg * 8;
    const short* Qrow = Qb + ((size_t)b * NN + j0 + rA) * NH + kg * 8;
    f32x4 acc = {0.f, 0.f, 0.f, 0.f};
    #pragma unroll
    for (int kc = 0; kc < 8; ++kc) {
        const bf16x8 av = *(const bf16x8*)(Prow + kc * 32);
        const bf16x8 bv = *(const bf16x8*)(Qrow + kc * 32);
        acc = __builtin_amdgcn_mfma_f32_16x16x32_bf16(av, bv, acc, 0, 0, 0);
    }
    const int j  = j0 + rA;
    const int gj = b * NN + j;
    const float4 stj = rowstats[gj];
    const float inv = 1.0f / NH;
    #pragma unroll
    for (int q = 0; q < 4; ++q) {
        const int i  = i0 + kg * 4 + q;
        const int gi = b * NN + i;
        const float4 sti = rowstats[gi];
        float a = adj[(size_t)gi * NN + j];
        if (j == i) a = 0.f;
        const float cd = acc[q];
        const float mu = (sti.x + stj.z) * inv;
        const float e2 = fmaf(2.f, cd, sti.y + stj.w) * inv;
        const float rr = __builtin_amdgcn_rsqf(fmaf(-mu, mu, e2) + LN_EPS);
        wmrG[(size_t)gi * NN + j] = make_float4(0.5f * a, rr, -mu * rr, a);
    }
}

// ---------------- K3: fused msg+node, 2 rows/block, 1024 blocks (packed-f32 edge loop) ----------------
__global__ __launch_bounds__(256, 4) void k_mn(
    const float* __restrict__ slots,
    const float* __restrict__ Pt,
    const float* __restrict__ Qm,
    const float4* __restrict__ wmrG,
    const float* __restrict__ ge,  const float* __restrict__ bge,
    const float* __restrict__ XW,
    const unsigned short* __restrict__ WCb, const float* __restrict__ v,
    const float* __restrict__ bn1,
    const float* __restrict__ gn,  const float* __restrict__ bgn,
    const unsigned short* __restrict__ Wn2b, const float* __restrict__ bn2,
    float* __restrict__ out)
{
    union U {
        struct { float4 wmr[2][NN]; float s[4][2][NH]; } e;
        struct { float sfg[2][NH];
                 union { float part[2][4][NH]; float d[2][8][ND + 4]; } w; } n;
    };
    __shared__ U u;
    __shared__ float lds_ws[2];
    __shared__ float lds_red[4][2][2];
    __shared__ float lds_mr[2][2];

    const int row0 = blockIdx.x * 2;
    const int b    = row0 >> 6;
    const int t    = threadIdx.x;
    const int lane = t & 63;
    const int wave = t >> 6;

    const float xw0 = XW[(size_t)row0 * NH + t];
    const float xw1 = XW[(size_t)(row0 + 1) * NH + t];
    const float sl  = slots[(size_t)(row0 + (t >> 7)) * ND + (t & 127)];
    if (t < 128) {
        const int r = t >> 6, j = t & 63;
        u.e.wmr[r][j] = wmrG[(size_t)(row0 + r) * NN + j];
    }
    const float4 P0 = ((const float4*)(Pt + (size_t)row0 * NH))[lane];
    const float4 P1 = ((const float4*)(Pt + (size_t)(row0 + 1) * NH))[lane];
    const float4 G  = ((const float4*)ge)[lane];
    const float4 Bg = ((const float4*)bge)[lane];
    // repack into f32x2 register pairs for packed math
    const f32x2 P0a = {P0.x, P0.y}, P0b = {P0.z, P0.w};
    const f32x2 P1a = {P1.x, P1.y}, P1b = {P1.z, P1.w};
    const f32x2 Ga  = {G.x,  G.y},  Gb  = {G.z,  G.w};
    const f32x2 Bga = {Bg.x, Bg.y}, Bgb = {Bg.z, Bg.w};
    __syncthreads();

    if (wave < 2) {
        float wv = u.e.wmr[wave][lane].w;
        #pragma unroll
        for (int off = 32; off; off >>= 1) wv += __shfl_xor(wv, off);
        if (lane == 0) lds_ws[wave] = wv;
    }

    // ---- edge main loop: packed 2-wide fp32 ----
    const float4* Qb4 = (const float4*)(Qm + (size_t)b * NN * NH) + lane;
    f32x2 A0a = {0.f, 0.f}, A0b = {0.f, 0.f};
    f32x2 A1a = {0.f, 0.f}, A1b = {0.f, 0.f};
    #pragma unroll 4
    for (int k = 0; k < 16; ++k) {
        const int jj = wave + 4 * k;
        const float4 q  = Qb4[jj * (NH / 4)];
        const f32x2 qa = {q.x, q.y}, qb = {q.z, q.w};
        const float4 m0 = u.e.wmr[0][jj];
        const float4 m1 = u.e.wmr[1][jj];
        {
            const f32x2 ha = P0a + qa;
            const f32x2 hb = P0b + qb;
            const f32x2 ua = (ha * m0.y + m0.z) * Ga + Bga;
            const f32x2 ub = (hb * m0.y + m0.z) * Gb + Bgb;
            A0a += m0.x * gelu2v(ua);
            A0b += m0.x * gelu2v(ub);
        }
        {
            const f32x2 ha = P1a + qa;
            const f32x2 hb = P1b + qb;
            const f32x2 ua = (ha * m1.y + m1.z) * Ga + Bga;
            const f32x2 ub = (hb * m1.y + m1.z) * Gb + Bgb;
            A1a += m1.x * gelu2v(ua);
            A1b += m1.x * gelu2v(ub);
        }
    }
    {
        float4 A0, A1;
        A0.x = A0a.x; A0.y = A0a.y; A0.z = A0b.x; A0.w = A0b.y;
        A1.x = A1a.x; A1.y = A1a.y; A1.z = A1b.x; A1.w = A1b.y;
        ((float4*)u.e.s[wave][0])[lane] = A0;
        ((float4*)u.e.s[wave][1])[lane] = A1;
    }
    __syncthreads();

    const float sf0 = (u.e.s[0][0][t] + u.e.s[1][0][t]) + (u.e.s[2][0][t] + u.e.s[3][0][t]);
    const float sf1 = (u.e.s[0][1][t] + u.e.s[1][1][t]) + (u.e.s[2][1][t] + u.e.s[3][1][t]);
    __syncthreads();
    u.n.sfg[0][t] = sf0;
    u.n.sfg[1][t] = sf1;
    __syncthreads();

    // ---- WC GEMV: bf16 weights, 4-way k-split ----
    {
        const int ks = wave;
        const int cg = lane;
        float4 h0 = make_float4(0.f, 0.f, 0.f, 0.f);
        float4 h1 = make_float4(0.f, 0.f, 0.f, 0.f);
        const uint2* wc2 = (const uint2*)WCb + cg;     // row = 64 uint2
        #pragma unroll 8
        for (int k = ks * 64; k < ks * 64 + 64; ++k) {
            const uint2 wp = wc2[k * 64];
            const float w0 = bflo(wp.x), w1 = bfhi(wp.x);
            const float w2v = bflo(wp.y), w3 = bfhi(wp.y);
            const float sa = u.n.sfg[0][k];
            const float sb = u.n.sfg[1][k];
            h0.x = fmaf(sa, w0, h0.x); h0.y = fmaf(sa, w1, h0.y);
            h0.z = fmaf(sa, w2v, h0.z); h0.w = fmaf(sa, w3, h0.w);
            h1.x = fmaf(sb, w0, h1.x); h1.y = fmaf(sb, w1, h1.y);
            h1.z = fmaf(sb, w2v, h1.z); h1.w = fmaf(sb, w3, h1.w);
        }
        ((float4*)u.n.w.part[0][ks])[cg] = h0;
        ((float4*)u.n.w.part[1][ks])[cg] = h1;
    }
    __syncthreads();

    float a0, a1;
    {
        const float b1 = bn1[t], vc = v[t];
        a0 = (u.n.w.part[0][0][t] + u.n.w.part[0][1][t])
           + (u.n.w.part[0][2][t] + u.n.w.part[0][3][t])
           + fmaf(lds_ws[0], vc, b1) + xw0;
        a1 = (u.n.w.part[1][0][t] + u.n.w.part[1][1][t])
           + (u.n.w.part[1][2][t] + u.n.w.part[1][3][t])
           + fmaf(lds_ws[1], vc, b1) + xw1;
    }
    {
        float s1 = a0, s2 = a0 * a0, s3 = a1, s4 = a1 * a1;
        #pragma unroll
        for (int off = 32; off; off >>= 1) {
            s1 += __shfl_xor(s1, off); s2 += __shfl_xor(s2, off);
            s3 += __shfl_xor(s3, off); s4 += __shfl_xor(s4, off);
        }
        if (lane == 0) {
            lds_red[wave][0][0] = s1; lds_red[wave][0][1] = s2;
            lds_red[wave][1][0] = s3; lds_red[wave][1][1] = s4;
        }
    }
    __syncthreads();
    if (t < 2) {
        const float S1 = (lds_red[0][t][0] + lds_red[1][t][0]) + (lds_red[2][t][0] + lds_red[3][t][0]);
        const float S2 = (lds_red[0][t][1] + lds_red[1][t][1]) + (lds_red[2][t][1] + lds_red[3][t][1]);
        const float mu  = S1 * (1.0f / NH);
        const float var = fmaf(-mu, mu, S2 * (1.0f / NH));
        lds_mr[t][0] = mu;
        lds_mr[t][1] = __builtin_amdgcn_rsqf(var + LN_EPS);
    }
    __syncthreads();
    {
        const float g = gn[t], bg = bgn[t];
        const float rr0 = lds_mr[0][1], rr1 = lds_mr[1][1];
        u.n.sfg[0][t] = gelu_h(fmaf(fmaf(a0, rr0, -lds_mr[0][0] * rr0), g, bg));
        u.n.sfg[1][t] = gelu_h(fmaf(fmaf(a1, rr1, -lds_mr[1][0] * rr1), g, bg));
    }
    __syncthreads();

    // ---- delta = g @ Wn2 (bf16 weights, 8-way k-split, both rows) ----
    {
        const int ks = t >> 5;
        const int cg = t & 31;
        float4 d0 = make_float4(0.f, 0.f, 0.f, 0.f);
        float4 d1 = make_float4(0.f, 0.f, 0.f, 0.f);
        const uint2* w2b = (const uint2*)Wn2b + cg;    // row = 32 uint2
        const int kbeg = ks * 32;
        #pragma unroll 8
        for (int k = kbeg; k < kbeg + 32; ++k) {
            const uint2 wp = w2b[k * 32];
            const float w0 = bflo(wp.x), w1 = bfhi(wp.x);
            const float w2v = bflo(wp.y), w3 = bfhi(wp.y);
            const float g0 = u.n.sfg[0][k];
            const float g1 = u.n.sfg[1][k];
            d0.x = fmaf(g0, w0, d0.x); d0.y = fmaf(g0, w1, d0.y);
            d0.z = fmaf(g0, w2v, d0.z); d0.w = fmaf(g0, w3, d0.w);
            d1.x = fmaf(g1, w0, d1.x); d1.y = fmaf(g1, w1, d1.y);
            d1.z = fmaf(g1, w2v, d1.z); d1.w = fmaf(g1, w3, d1.w);
        }
        ((float4*)u.n.w.d[0][ks])[cg] = d0;
        ((float4*)u.n.w.d[1][ks])[cg] = d1;
    }
    __syncthreads();
    {
        const int r  = t >> 7;
        const int c2 = t & 127;
        float ds = 0.f;
        #pragma unroll
        for (int p2 = 0; p2 < 8; ++p2) ds += u.n.w.d[r][p2][c2];
        out[(size_t)(row0 + r) * ND + c2] = sl + bn2[c2] + ds;
    }
}

extern "C" void kernel_launch(void* const* d_in, const int* in_sizes, int n_in,
                              void* d_out, int out_size, void* d_ws, size_t ws_size,
                              hipStream_t stream) {
    const float* slots = (const float*)d_in[0];
    const float* adj   = (const float*)d_in[1];
    const float* We1   = (const float*)d_in[2];
    const float* be1   = (const float*)d_in[3];
    const float* ge    = (const float*)d_in[4];
    const float* bge   = (const float*)d_in[5];
    const float* We2   = (const float*)d_in[6];
    const float* be2   = (const float*)d_in[7];
    const float* Wn1   = (const float*)d_in[8];
    const float* bn1   = (const float*)d_in[9];
    const float* gn    = (const float*)d_in[10];
    const float* bgn   = (const float*)d_in[11];
    const float* Wn2   = (const float*)d_in[12];
    const float* bn2   = (const float*)d_in[13];
    float* out = (float*)d_out;

    const size_t RN = (size_t)NB * NN;          // 2048
    float*  Ptw  = (float*)d_ws;                // [2048,256] f32
    float*  Qw   = Ptw  + RN * NH;              // [2048,256] f32
    float*  XWw  = Qw   + RN * NH;              // [2048,256] f32
    float*  vw   = XWw  + RN * NH;              // [256]
    float4* rsw  = (float4*)(vw + NH + 768);    // [2048] (16B aligned: 256+768=1024 floats)
    float4* wmrw = rsw + RN;                    // [2048*64]
    short*  Pbw  = (short*)(wmrw + RN * NN);    // [2048,256] bf16
    short*  Qbw  = Pbw + RN * NH;               // [2048,256] bf16
    unsigned short* WCbw  = (unsigned short*)(Qbw + RN * NH);   // [256,256] bf16
    unsigned short* Wn2bw = WCbw + (size_t)NH * NH;             // [256,128] bf16

    k_pre<<<581,            256, 0, stream>>>(slots, We1, be1, Wn1, We2, be2, Wn2,
                                              Ptw, Qw, XWw, Pbw, Qbw, rsw, WCbw, vw, Wn2bw);
    k_dot<<<NB * 4,         256, 0, stream>>>(Pbw, Qbw, rsw, adj, wmrw);
    k_mn <<<(int)(RN / 2),  256, 0, stream>>>(slots, Ptw, Qw, wmrw, ge, bge,
                                              XWw, WCbw, vw, bn1, gn, bgn, Wn2bw, bn2, out);
}